// Round 6
// baseline (141.861 us; speedup 1.0000x reference)
//
#include <hip/hip_runtime.h>

// MetaUpSampler via bf16 MFMA — round 13 (= R12 kernels, meta launched 2x).
// MEASUREMENT ROUND. R10/R11/R12 = 118.2/118.7/118.6 — three structurally
// different kernels, three nulls. Two decompositions conflict:
//   (a) R7 anchor (meta measured 45.2 -> F~83) => meta ~23us, still fat;
//   (b) R12's exact null under 2x TLP => meta ~10us, total is harness floor.
// Discriminator: launch the identical validated meta TWICE (idempotent:
// same inputs, same deterministic output). dur_R13 - dur_R12 = meta + gap.
//   (a) => dur ~141-144 -> next round attacks meta phase serialization.
//   (b) => dur ~127-131 -> controllable part is near floor; declare roofline.
// Kernels are byte-identical to R12 (validated) for a clean A/B.
// Workspace: lwb @ 0 (55KB), xt @ +64KB (18.9MB).

#define HH   192
#define WWD  192
#define SS   4
#define OC   3
#define PO   48
#define HID  256
#define W2LD 1728

typedef short  bf16x8 __attribute__((ext_vector_type(8)));
typedef float  f32x4  __attribute__((ext_vector_type(4)));

static __device__ __forceinline__ short f2bf(float f) {
    unsigned u = __float_as_uint(f);
    unsigned r = (u + 0x7fffu + ((u >> 16) & 1u)) >> 16;   // RNE
    return (short)r;
}

static __device__ __forceinline__ void pin(bf16x8& v) {
    asm volatile("" : "+v"(v));    // force VGPR residency; block load sinking
}

// ---------------- Stage A (fused): MLP -> weights  +  x -> NHWC bf16 -------
__global__ __launch_bounds__(256) void prep_kernel(
        const float* __restrict__ x,
        const float* __restrict__ W1, const float* __restrict__ b1,
        const float* __restrict__ W2, const float* __restrict__ b2,
        short* __restrict__ lwb, short* __restrict__ xt) {
    const int b = blockIdx.x;
    const int t = threadIdx.x;
    if (b < 112) {
        __shared__ float hlds[HID];
        const int p = b / 7;
        {
            const float pi = (float)(p >> 2) * 0.25f;
            const float pj = (float)(p & 3) * 0.25f;
            const float v = 0.25f * W1[t] + pi * W1[HID + t] + pj * W1[2 * HID + t]
                          + b1[t];
            hlds[t] = v > 0.f ? v : 0.f;
        }
        __syncthreads();
        const int col = (b % 7) * 256 + t;   // 0..1791 (guard at 1728)
        if (col < W2LD) {
            float a = 0.f;
#pragma unroll 32
            for (int hh = 0; hh < HID; ++hh)
                a += hlds[hh] * W2[hh * W2LD + col];   // coalesced 4B + LDS bcast
            const int o = col % 3, kc = col / 3;
            const int tap = kc % 9, c = kc / 9;
            lwb[(tap * PO + p * 3 + o) * 64 + c] = f2bf(a + b2[col]);
        }
    } else {
        __shared__ short tl[64][72];         // [w][c], +8 pad vs bank stride
        const int bb = b - 112;
        const int wt = bb % 3;
        const int h  = (bb / 3) % HH;
        const int n  = bb / (3 * HH);
        const int w0 = wt * 64;
#pragma unroll
        for (int i = 0; i < 4; ++i) {
            const int idx = i * 256 + t;     // 0..1023
            const int c   = idx >> 4;        // channel 0..63
            const int j4  = idx & 15;        // float4 within 64 w
            const float4 v = *(const float4*)
                &x[(((size_t)(n * 64 + c)) * HH + h) * WWD + w0 + j4 * 4];
            tl[j4 * 4 + 0][c] = f2bf(v.x);
            tl[j4 * 4 + 1][c] = f2bf(v.y);
            tl[j4 * 4 + 2][c] = f2bf(v.z);
            tl[j4 * 4 + 3][c] = f2bf(v.w);
        }
        __syncthreads();
        const int w  = t >> 2;
        const int c0 = (t & 3) * 16;
        short* dst = &xt[(((size_t)n * HH + h) * WWD + w0 + w) * 64 + c0];
        *(bf16x8*)&dst[0] = *(const bf16x8*)&tl[w][c0];
        *(bf16x8*)&dst[8] = *(const bf16x8*)&tl[w][c0 + 8];
    }
}

// ---------------- Stage B: MFMA dynamic conv, 3 h-rows, 6 waves ------------
__global__ __launch_bounds__(384) void meta_up_mfma(
        const short* __restrict__ xt, const short* __restrict__ lwb,
        float* __restrict__ out) {
    __shared__ __align__(16) short smem[5 * 66 * 64];   // 42,240 B
    short* xlds = smem;                    // [r][j][c], c in XOR'd 16B blocks
    float* obuf = (float*)smem;            // reused post-MFMA: 36 x 260 floats

    const int g   = (blockIdx.x & 7) * 96 + (blockIdx.x >> 3);
    const int n   = g / 192;
    const int rem = g % 192;
    const int wch = rem / 64;
    const int hg  = rem % 64;
    const int h0  = hg * 3;
    const int w0  = wch * 64;

    const int tid  = threadIdx.x;
    const int lane = tid & 63;
    const int wv   = (tid >> 6) % 3;              // po-tile
    const int wgq  = (tid >> 6) / 3;              // m-tile half
    const int quad = lane >> 4, l15 = lane & 15;

    bf16x8 Bb[2][3];
#pragma unroll
    for (int di = 0; di < 3; ++di) {               // phase 0 (dj=0,kc=0)
        Bb[0][di] = *(const bf16x8*)
            &lwb[((di * 3 + 0) * PO + wv * 16 + l15) * 64 + 0 * 32 + quad * 8];
        pin(Bb[0][di]);
    }

    // Stage 5 rows x 66 cols x 8 cb = 2640 16B-items, flat over 384 threads.
    {
        const bf16x8 z = {0, 0, 0, 0, 0, 0, 0, 0};
#pragma unroll
        for (int k = 0; k < 7; ++k) {
            const int item = k * 384 + tid;
            if (item < 2640) {
                const int r   = item / 528;          // 0..4
                const int rm  = item - r * 528;
                const int j   = rm >> 3;             // 0..65
                const int cb  = rm & 7;
                const int gr  = h0 - 1 + r;
                const int gc  = w0 - 1 + j;
                const bool ok = ((unsigned)gr < (unsigned)HH) &&
                                ((unsigned)gc < (unsigned)WWD);
                const bf16x8 v = ok ? *(const bf16x8*)
                    &xt[((size_t)(n * HH + gr) * WWD + gc) * 64 + cb * 8] : z;
                *(bf16x8*)&xlds[(r * 66 + j) * 64 + ((cb ^ (j & 7)) << 3)] = v;
            }
        }
    }
    __syncthreads();

    f32x4 acc[3][2];
#pragma unroll
    for (int ih = 0; ih < 3; ++ih)
#pragma unroll
        for (int mtl = 0; mtl < 2; ++mtl) acc[ih][mtl] = (f32x4){0.f, 0.f, 0.f, 0.f};

#pragma unroll
    for (int b = 0; b < 6; ++b) {
        const int dj = b >> 1, kc2 = b & 1;
        if (b < 5) {                                 // rolling B prefetch
            const int djn = (b + 1) >> 1, kcn = (b + 1) & 1;
#pragma unroll
            for (int di = 0; di < 3; ++di) {
                Bb[(b + 1) & 1][di] = *(const bf16x8*)
                    &lwb[((di * 3 + djn) * PO + wv * 16 + l15) * 64 + kcn * 32 + quad * 8];
                pin(Bb[(b + 1) & 1][di]);
            }
        }
#pragma unroll
        for (int mtl = 0; mtl < 2; ++mtl) {
            const int mt  = wgq * 2 + mtl;
            const int col = mt * 16 + l15 + dj;      // 0..65
            const int blk = (kc2 * 4 + quad) ^ (col & 7);
#pragma unroll
            for (int r = 0; r < 5; ++r) {
                bf16x8 a = *(const bf16x8*)&xlds[(r * 66 + col) * 64 + (blk << 3)];
#pragma unroll
                for (int di = 0; di < 3; ++di) {
                    const int ih = r - di;
                    if (ih >= 0 && ih < 3)
                        acc[ih][mtl] = __builtin_amdgcn_mfma_f32_16x16x32_bf16(
                            a, Bb[b & 1][di], acc[ih][mtl], 0, 0, 0);
                }
            }
        }
    }

    __syncthreads();                       // all xlds reads complete
    {
        const int po = wv * 16 + l15;
        const int o  = po % 3;
        const int p  = po / 3;
        const int si = p >> 2, sj = p & 3;
        const int osi = o * 4 + si;
#pragma unroll
        for (int ih = 0; ih < 3; ++ih)
#pragma unroll
            for (int mtl = 0; mtl < 2; ++mtl) {
                const int mt = wgq * 2 + mtl;
#pragma unroll
                for (int r4 = 0; r4 < 4; ++r4) {
                    const int wl = mt * 16 + quad * 4 + r4;
                    obuf[(ih * 12 + osi) * 260 + wl * 4 + sj] = acc[ih][mtl][r4];
                }
            }
    }
    __syncthreads();
    {
#pragma unroll
        for (int ih = 0; ih < 3; ++ih)
#pragma unroll
            for (int h2 = 0; h2 < 2; ++h2) {
                const int idx = h2 * 384 + tid;      // 0..767
                const int osi = idx >> 6;            // 0..11
                const int c4  = idx & 63;
                const int o = osi >> 2, si = osi & 3;
                const int hh = h0 + ih;
                const size_t base =
                    ((size_t)(n * OC + o) * (SS * HH) + (size_t)(SS * hh + si))
                        * (SS * WWD) + (size_t)(4 * w0) + c4 * 4;
                *(float4*)&out[base] =
                    *(const float4*)&obuf[(ih * 12 + osi) * 260 + c4 * 4];
            }
    }
}

extern "C" void kernel_launch(void* const* d_in, const int* in_sizes, int n_in,
                              void* d_out, int out_size, void* d_ws, size_t ws_size,
                              hipStream_t stream) {
    const float* x  = (const float*)d_in[0];
    const float* W1 = (const float*)d_in[1];
    const float* b1 = (const float*)d_in[2];
    const float* W2 = (const float*)d_in[3];
    const float* b2 = (const float*)d_in[4];
    float* out = (float*)d_out;
    short* lwb = (short*)d_ws;                  // 27,648 bf16 = 55 KB
    short* xt  = (short*)d_ws + 32768;          // NHWC bf16 x, 18.9 MB

    prep_kernel<<<112 + 4 * HH * 3, 256, 0, stream>>>(x, W1, b1, W2, b2, lwb, xt);
    // MEASUREMENT: meta launched twice (idempotent). dur - dur_R12 = meta+gap.
    meta_up_mfma<<<768, 384, 0, stream>>>(xt, lwb, out);
    meta_up_mfma<<<768, 384, 0, stream>>>(xt, lwb, out);
}

// Round 7
// 112.977 us; speedup vs baseline: 1.2557x; 1.2557x over previous
//
#include <hip/hip_runtime.h>

// MetaUpSampler via bf16 MFMA — round 14 (persistent 3-tile pipelined meta).
// R13 measurement: meta = 23.3us - gap ~= 22us, AND TLP-insensitive (R12 2x
//   waves = exact null). Diagnosis: 768 blocks all co-resident & phase-LOCKED
//   -> chip-wide serialized bursts: stage(HBM) ; MFMA(LDS) ; store(HBM).
// R14 fix: 256 persistent blocks (1/CU), 3 XCD-local consecutive tiles each,
//   software-pipelined: issue loads(t+1) -> MFMA(t) -> stores(t) ->
//   ds_write(t+1). Double-buffered xlds (2x42.2KB) + separate obuf (37.4KB)
//   = 121.9KB LDS. Steady state = max(mem, compute), not sum. B-fragments
//   are tile-invariant -> loaded ONCE (18 pinned; VGPR can't hurt occupancy
//   at 1 block/CU). LDS image/swizzle/MFMA loop/epilogue identical to R12.
// Workspace: lwb @ 0 (55KB), xt @ +64KB (18.9MB).

#define HH   192
#define WWD  192
#define SS   4
#define OC   3
#define PO   48
#define HID  256
#define W2LD 1728
#define BUFS 21120   // shorts per xlds buffer: 5*66*64

typedef short  bf16x8 __attribute__((ext_vector_type(8)));
typedef float  f32x4  __attribute__((ext_vector_type(4)));

static __device__ __forceinline__ short f2bf(float f) {
    unsigned u = __float_as_uint(f);
    unsigned r = (u + 0x7fffu + ((u >> 16) & 1u)) >> 16;   // RNE
    return (short)r;
}

static __device__ __forceinline__ void pin(bf16x8& v) {
    asm volatile("" : "+v"(v));    // force VGPR residency; block load sinking
}

// ---------------- Stage A (fused): MLP -> weights  +  x -> NHWC bf16 -------
__global__ __launch_bounds__(256) void prep_kernel(
        const float* __restrict__ x,
        const float* __restrict__ W1, const float* __restrict__ b1,
        const float* __restrict__ W2, const float* __restrict__ b2,
        short* __restrict__ lwb, short* __restrict__ xt) {
    const int b = blockIdx.x;
    const int t = threadIdx.x;
    if (b < 112) {
        __shared__ float hlds[HID];
        const int p = b / 7;
        {
            const float pi = (float)(p >> 2) * 0.25f;
            const float pj = (float)(p & 3) * 0.25f;
            const float v = 0.25f * W1[t] + pi * W1[HID + t] + pj * W1[2 * HID + t]
                          + b1[t];
            hlds[t] = v > 0.f ? v : 0.f;
        }
        __syncthreads();
        const int col = (b % 7) * 256 + t;   // 0..1791 (guard at 1728)
        if (col < W2LD) {
            float a = 0.f;
#pragma unroll 32
            for (int hh = 0; hh < HID; ++hh)
                a += hlds[hh] * W2[hh * W2LD + col];   // coalesced 4B + LDS bcast
            const int o = col % 3, kc = col / 3;
            const int tap = kc % 9, c = kc / 9;
            lwb[(tap * PO + p * 3 + o) * 64 + c] = f2bf(a + b2[col]);
        }
    } else {
        __shared__ short tl[64][72];         // [w][c], +8 pad vs bank stride
        const int bb = b - 112;
        const int wt = bb % 3;
        const int h  = (bb / 3) % HH;
        const int n  = bb / (3 * HH);
        const int w0 = wt * 64;
#pragma unroll
        for (int i = 0; i < 4; ++i) {
            const int idx = i * 256 + t;     // 0..1023
            const int c   = idx >> 4;        // channel 0..63
            const int j4  = idx & 15;        // float4 within 64 w
            const float4 v = *(const float4*)
                &x[(((size_t)(n * 64 + c)) * HH + h) * WWD + w0 + j4 * 4];
            tl[j4 * 4 + 0][c] = f2bf(v.x);
            tl[j4 * 4 + 1][c] = f2bf(v.y);
            tl[j4 * 4 + 2][c] = f2bf(v.z);
            tl[j4 * 4 + 3][c] = f2bf(v.w);
        }
        __syncthreads();
        const int w  = t >> 2;
        const int c0 = (t & 3) * 16;
        short* dst = &xt[(((size_t)n * HH + h) * WWD + w0 + w) * 64 + c0];
        *(bf16x8*)&dst[0] = *(const bf16x8*)&tl[w][c0];
        *(bf16x8*)&dst[8] = *(const bf16x8*)&tl[w][c0 + 8];
    }
}

// ---------------- Stage B: persistent pipelined MFMA dynamic conv ----------
__global__ __launch_bounds__(384) void meta_up_mfma(
        const short* __restrict__ xt, const short* __restrict__ lwb,
        float* __restrict__ out) {
    // 2 xlds buffers + separate obuf: 84,480 + 37,440 = 121,920 B.
    __shared__ __align__(16) short smem[2 * BUFS + 18720];
    float* obuf = (float*)&smem[2 * BUFS];

    const int xcd = blockIdx.x & 7;       // HW: block b -> XCD b%8
    const int ii  = blockIdx.x >> 3;      // 0..31 within XCD
    const int tid = threadIdx.x;
    const int lane = tid & 63;
    const int wv   = (tid >> 6) % 3;      // po-tile
    const int wgq  = (tid >> 6) / 3;      // m-tile half
    const int quad = lane >> 4, l15 = lane & 15;

    // B fragments: tile-invariant -> load all 18 once, pin to VGPRs.
    bf16x8 Bf[18];
#pragma unroll
    for (int tap = 0; tap < 9; ++tap)
#pragma unroll
        for (int kc2 = 0; kc2 < 2; ++kc2)
            Bf[tap * 2 + kc2] = *(const bf16x8*)
                &lwb[(tap * PO + wv * 16 + l15) * 64 + kc2 * 32 + quad * 8];
#pragma unroll
    for (int i = 0; i < 18; ++i) pin(Bf[i]);

    // Tile decode: tau = 96*xcd + 3*ii + t, t = 0..2 (consecutive hg ->
    // tile t+1's rows are L2-warm from tile t's reads).
    int n_c, h0_c, w0_c;                  // current-tile params
    {
        const int tau = 96 * xcd + 3 * ii;
        n_c = tau / 192;
        const int rem = tau % 192;
        w0_c = (rem / 64) * 64;
        h0_c = (rem % 64) * 3;
    }

    const bf16x8 z = {0, 0, 0, 0, 0, 0, 0, 0};
    bf16x8 sv[7];

    // ---- stage-load tile 0 into regs, write buf0, barrier ------------------
#pragma unroll
    for (int k = 0; k < 7; ++k) {
        const int item = k * 384 + tid;
        const int r  = item / 528;
        const int rm = item - r * 528;
        const int j  = rm >> 3, cb = rm & 7;
        const int gr = h0_c - 1 + r, gc = w0_c - 1 + j;
        const bool ok = (item < 2640) && ((unsigned)gr < (unsigned)HH) &&
                        ((unsigned)gc < (unsigned)WWD);
        sv[k] = ok ? *(const bf16x8*)
            &xt[((size_t)(n_c * HH + gr) * WWD + gc) * 64 + cb * 8] : z;
    }
#pragma unroll
    for (int k = 0; k < 7; ++k) {
        const int item = k * 384 + tid;
        if (item < 2640) {
            const int r  = item / 528;
            const int rm = item - r * 528;
            const int j  = rm >> 3, cb = rm & 7;
            *(bf16x8*)&smem[(r * 66 + j) * 64 + ((cb ^ (j & 7)) << 3)] = sv[k];
        }
    }
    __syncthreads();

    for (int t = 0; t < 3; ++t) {
        int n_n = n_c, h0_n = h0_c, w0_n = w0_c;
        if (t < 2) {
            // decode tile t+1 and ISSUE its loads (hide under MFMA+epilogue)
            const int tau = 96 * xcd + 3 * ii + t + 1;
            n_n = tau / 192;
            const int rem = tau % 192;
            w0_n = (rem / 64) * 64;
            h0_n = (rem % 64) * 3;
#pragma unroll
            for (int k = 0; k < 7; ++k) {
                const int item = k * 384 + tid;
                const int r  = item / 528;
                const int rm = item - r * 528;
                const int j  = rm >> 3, cb = rm & 7;
                const int gr = h0_n - 1 + r, gc = w0_n - 1 + j;
                const bool ok = (item < 2640) && ((unsigned)gr < (unsigned)HH) &&
                                ((unsigned)gc < (unsigned)WWD);
                sv[k] = ok ? *(const bf16x8*)
                    &xt[((size_t)(n_n * HH + gr) * WWD + gc) * 64 + cb * 8] : z;
            }
        }

        // ---- MFMA phase on buffer t&1 (validated R12 loop) ----------------
        const short* __restrict__ xb = &smem[(t & 1) * BUFS];
        f32x4 acc[3][2];
#pragma unroll
        for (int ih = 0; ih < 3; ++ih)
#pragma unroll
            for (int mtl = 0; mtl < 2; ++mtl)
                acc[ih][mtl] = (f32x4){0.f, 0.f, 0.f, 0.f};

#pragma unroll
        for (int b = 0; b < 6; ++b) {
            const int dj = b >> 1, kc2 = b & 1;
#pragma unroll
            for (int mtl = 0; mtl < 2; ++mtl) {
                const int mt  = wgq * 2 + mtl;
                const int col = mt * 16 + l15 + dj;      // 0..65
                const int blk = (kc2 * 4 + quad) ^ (col & 7);
#pragma unroll
                for (int r = 0; r < 5; ++r) {
                    bf16x8 a = *(const bf16x8*)&xb[(r * 66 + col) * 64 + (blk << 3)];
#pragma unroll
                    for (int di = 0; di < 3; ++di) {
                        const int ih = r - di;
                        if (ih >= 0 && ih < 3)
                            acc[ih][mtl] = __builtin_amdgcn_mfma_f32_16x16x32_bf16(
                                a, Bf[(di * 3 + dj) * 2 + kc2], acc[ih][mtl], 0, 0, 0);
                    }
                }
            }
        }

        // ---- epilogue: D -> obuf (separate LDS; no clash with xlds) -------
        {
            const int po = wv * 16 + l15;
            const int o  = po % 3;
            const int p  = po / 3;
            const int si = p >> 2, sj = p & 3;
            const int osi = o * 4 + si;
#pragma unroll
            for (int ih = 0; ih < 3; ++ih)
#pragma unroll
                for (int mtl = 0; mtl < 2; ++mtl) {
                    const int mt = wgq * 2 + mtl;
#pragma unroll
                    for (int r4 = 0; r4 < 4; ++r4) {
                        const int wl = mt * 16 + quad * 4 + r4;
                        obuf[(ih * 12 + osi) * 260 + wl * 4 + sj] = acc[ih][mtl][r4];
                    }
                }
        }
        __syncthreads();                   // obuf visible (also drains t's reads)

        // ---- coalesced out stores (overlap next tile's loads in HBM) ------
#pragma unroll
        for (int ih = 0; ih < 3; ++ih)
#pragma unroll
            for (int h2 = 0; h2 < 2; ++h2) {
                const int idx = h2 * 384 + tid;      // 0..767
                const int osi = idx >> 6;            // 0..11
                const int c4  = idx & 63;
                const int o = osi >> 2, si = osi & 3;
                const int hh = h0_c + ih;
                const size_t base =
                    ((size_t)(n_c * OC + o) * (SS * HH) + (size_t)(SS * hh + si))
                        * (SS * WWD) + (size_t)(4 * w0_c) + c4 * 4;
                *(float4*)&out[base] =
                    *(const float4*)&obuf[(ih * 12 + osi) * 260 + c4 * 4];
            }

        if (t < 2) {
            // ds_write tile t+1 into the OTHER buffer (no WAR with MFMA(t))
#pragma unroll
            for (int k = 0; k < 7; ++k) {
                const int item = k * 384 + tid;
                if (item < 2640) {
                    const int r  = item / 528;
                    const int rm = item - r * 528;
                    const int j  = rm >> 3, cb = rm & 7;
                    *(bf16x8*)&smem[((t + 1) & 1) * BUFS +
                        (r * 66 + j) * 64 + ((cb ^ (j & 7)) << 3)] = sv[k];
                }
            }
            __syncthreads();               // buf(t+1) visible before MFMA(t+1)
            n_c = n_n; h0_c = h0_n; w0_c = w0_n;
        }
    }
}

extern "C" void kernel_launch(void* const* d_in, const int* in_sizes, int n_in,
                              void* d_out, int out_size, void* d_ws, size_t ws_size,
                              hipStream_t stream) {
    const float* x  = (const float*)d_in[0];
    const float* W1 = (const float*)d_in[1];
    const float* b1 = (const float*)d_in[2];
    const float* W2 = (const float*)d_in[3];
    const float* b2 = (const float*)d_in[4];
    float* out = (float*)d_out;
    short* lwb = (short*)d_ws;                  // 27,648 bf16 = 55 KB
    short* xt  = (short*)d_ws + 32768;          // NHWC bf16 x, 18.9 MB

    prep_kernel<<<112 + 4 * HH * 3, 256, 0, stream>>>(x, W1, b1, W2, b2, lwb, xt);
    meta_up_mfma<<<256, 384, 0, stream>>>(xt, lwb, out);
}